// Round 2
// baseline (7836.567 us; speedup 1.0000x reference)
//
#include <hip/hip_runtime.h>
#include <hip/hip_bf16.h>

// Problem constants
#define BATCH 64
#define TT 512
#define UNITS 512
#define NOUT 256
#define NSPEED 20
#define NHD 50
#define NFEAT 70

// Derived constants
#define SPEED_COEF (-800.0f)                  // -0.5/sd^2, sd = 0.5/20
#define SPEED_STEP (0.5f / 19.0f)             // linspace(0,0.5,20)
#define HD_STEP (6.28318530718f / 49.0f)      // linspace(0,2pi,50)
#define KAPPA 6.2831853f
#define C_HD 0.9783857f                       // 1 / (2*pi*i0e(2*pi)), i0e(2pi)=0.162671

// ---------------------------------------------------------------------------
// Kernel A: RBF/VonMises features + drive = sf@W_speed + hf@W_hd + b_rec
// grid 512 blocks x 256 threads; each block does 64 rows (row = b*T + t)
// ---------------------------------------------------------------------------
__global__ __launch_bounds__(256) void feat_drive_kernel(
    const float* __restrict__ vel, const float* __restrict__ W_speed,
    const float* __restrict__ W_hd, const float* __restrict__ b_rec,
    float* __restrict__ drive) {
  __shared__ float feats[64][NFEAT];
  const int row0 = blockIdx.x * 64;
  const int tid = threadIdx.x;

  for (int j = tid; j < 64 * NFEAT; j += 256) {
    int row = j / NFEAT, k = j % NFEAT;
    int grow = row0 + row;
    float f;
    if (k < NSPEED) {
      float s = vel[grow * 2 + 0];
      float d = s - (float)k * SPEED_STEP;
      f = __expf(SPEED_COEF * d * d);
    } else {
      float hd = vel[grow * 2 + 1];
      float c = (float)(k - NSPEED) * HD_STEP;
      f = C_HD * __expf(KAPPA * (__cosf(hd - c) - 1.0f));
    }
    feats[row][k] = f;
  }
  __syncthreads();

  const float2* Ws2 = (const float2*)W_speed;  // [20][256]
  const float2* Wh2 = (const float2*)W_hd;     // [50][256]
  float2 br = ((const float2*)b_rec)[tid];

  for (int r = 0; r < 64; ++r) {
    float a0 = br.x, a1 = br.y;
#pragma unroll
    for (int k = 0; k < NSPEED; ++k) {
      float f = feats[r][k];
      float2 w = Ws2[k * 256 + tid];
      a0 = fmaf(f, w.x, a0);
      a1 = fmaf(f, w.y, a1);
    }
#pragma unroll 10
    for (int k = 0; k < NHD; ++k) {
      float f = feats[r][NSPEED + k];
      float2 w = Wh2[k * 256 + tid];
      a0 = fmaf(f, w.x, a0);
      a1 = fmaf(f, w.y, a1);
    }
    ((float2*)drive)[(size_t)(row0 + r) * 256 + tid] = make_float2(a0, a1);
  }
}

// ---------------------------------------------------------------------------
// Kernel B: sequential RNN scan, one block per batch element.
// h double-buffered in LDS; thread owns 2 output columns (float2).
// ---------------------------------------------------------------------------
__global__ __launch_bounds__(256) void rnn_scan_kernel(
    const float* __restrict__ drive, const float* __restrict__ W_rec,
    const float* __restrict__ start_state, float* __restrict__ hstates) {
  __shared__ float hbuf[2][UNITS];
  const int b = blockIdx.x;
  const int tid = threadIdx.x;

  ((float2*)hbuf[0])[tid] = ((const float2*)start_state)[tid];
  __syncthreads();

  const float2* W2 = (const float2*)W_rec;  // [512][256] float2
  const float2* D2 = (const float2*)drive + (size_t)b * TT * 256;
  float2* H2 = (float2*)hstates + (size_t)b * TT * 256;

  int cur = 0;
  for (int t = 0; t < TT; ++t) {
    const float* h = hbuf[cur];
    float a0 = 0.0f, a1 = 0.0f;
#pragma unroll 4
    for (int k = 0; k < UNITS; k += 4) {
      float4 hv = *(const float4*)(h + k);
      float2 w0 = W2[(k + 0) * 256 + tid];
      float2 w1 = W2[(k + 1) * 256 + tid];
      float2 w2 = W2[(k + 2) * 256 + tid];
      float2 w3 = W2[(k + 3) * 256 + tid];
      a0 = fmaf(hv.x, w0.x, a0); a1 = fmaf(hv.x, w0.y, a1);
      a0 = fmaf(hv.y, w1.x, a0); a1 = fmaf(hv.y, w1.y, a1);
      a0 = fmaf(hv.z, w2.x, a0); a1 = fmaf(hv.z, w2.y, a1);
      a0 = fmaf(hv.w, w3.x, a0); a1 = fmaf(hv.w, w3.y, a1);
    }
    float2 d = D2[t * 256 + tid];
    float2 hn = make_float2(fmaxf(a0 + d.x, 0.0f), fmaxf(a1 + d.y, 0.0f));
    ((float2*)hbuf[cur ^ 1])[tid] = hn;
    H2[t * 256 + tid] = hn;
    cur ^= 1;
    __syncthreads();
  }
}

// ---------------------------------------------------------------------------
// Kernel C: out = relu(hstates @ W_out + b_out); M=32768, N=256, K=512
// 64x64 tile per block, 256 threads, 4x4 per thread, BK=32.
// ---------------------------------------------------------------------------
__global__ __launch_bounds__(256) void out_gemm_kernel(
    const float* __restrict__ A,    // [32768][512]
    const float* __restrict__ Bm,   // [512][256]
    const float* __restrict__ b_out,
    float* __restrict__ C) {        // [32768][256]
  __shared__ float As[32][68];  // transposed, padded
  __shared__ float Bs[32][64];
  const int bm = blockIdx.x, bn = blockIdx.y;
  const int tid = threadIdx.x;
  const int tm = tid / 16, tn = tid % 16;

  float acc[4][4] = {{0.f}};

  for (int k0 = 0; k0 < UNITS; k0 += 32) {
    {
      int ar = tid / 8;
      int ac = (tid % 8) * 4;
#pragma unroll
      for (int p = 0; p < 2; ++p) {
        int row = ar + p * 32;
        float4 v = *(const float4*)&A[(size_t)(bm * 64 + row) * 512 + k0 + ac];
        As[ac + 0][row] = v.x;
        As[ac + 1][row] = v.y;
        As[ac + 2][row] = v.z;
        As[ac + 3][row] = v.w;
      }
      int brr = tid / 16;
      int bc = (tid % 16) * 4;
#pragma unroll
      for (int p = 0; p < 2; ++p) {
        int row = brr + p * 16;
        *(float4*)&Bs[row][bc] =
            *(const float4*)&Bm[(size_t)(k0 + row) * 256 + bn * 64 + bc];
      }
    }
    __syncthreads();
#pragma unroll
    for (int kk = 0; kk < 32; ++kk) {
      float4 av = *(const float4*)&As[kk][tm * 4];
      float4 bv = *(const float4*)&Bs[kk][tn * 4];
      acc[0][0] = fmaf(av.x, bv.x, acc[0][0]);
      acc[0][1] = fmaf(av.x, bv.y, acc[0][1]);
      acc[0][2] = fmaf(av.x, bv.z, acc[0][2]);
      acc[0][3] = fmaf(av.x, bv.w, acc[0][3]);
      acc[1][0] = fmaf(av.y, bv.x, acc[1][0]);
      acc[1][1] = fmaf(av.y, bv.y, acc[1][1]);
      acc[1][2] = fmaf(av.y, bv.z, acc[1][2]);
      acc[1][3] = fmaf(av.y, bv.w, acc[1][3]);
      acc[2][0] = fmaf(av.z, bv.x, acc[2][0]);
      acc[2][1] = fmaf(av.z, bv.y, acc[2][1]);
      acc[2][2] = fmaf(av.z, bv.z, acc[2][2]);
      acc[2][3] = fmaf(av.z, bv.w, acc[2][3]);
      acc[3][0] = fmaf(av.w, bv.x, acc[3][0]);
      acc[3][1] = fmaf(av.w, bv.y, acc[3][1]);
      acc[3][2] = fmaf(av.w, bv.z, acc[3][2]);
      acc[3][3] = fmaf(av.w, bv.w, acc[3][3]);
    }
    __syncthreads();
  }

  float4 bo = *(const float4*)&b_out[bn * 64 + tn * 4];
#pragma unroll
  for (int i = 0; i < 4; ++i) {
    int row = bm * 64 + tm * 4 + i;
    float4 o;
    o.x = fmaxf(acc[i][0] + bo.x, 0.0f);
    o.y = fmaxf(acc[i][1] + bo.y, 0.0f);
    o.z = fmaxf(acc[i][2] + bo.z, 0.0f);
    o.w = fmaxf(acc[i][3] + bo.w, 0.0f);
    *(float4*)&C[(size_t)row * 256 + bn * 64 + tn * 4] = o;
  }
}

// ---------------------------------------------------------------------------
// Kernel D1: EC[b,n,:] = (sum_t out*r) / (sum_t out + T*1e-10)
// ---------------------------------------------------------------------------
__global__ __launch_bounds__(256) void ec_kernel(
    const float* __restrict__ out, const float* __restrict__ r,
    float* __restrict__ EC) {  // [64][256][2]
  const int b = blockIdx.x, n = threadIdx.x;
  const float* ob = out + (size_t)b * TT * NOUT;
  const float2* rb = (const float2*)r + (size_t)b * TT;
  float s = 0.0f, e0 = 0.0f, e1 = 0.0f;
  for (int t = 0; t < TT; ++t) {
    float o = ob[t * NOUT + n];
    float2 rv = rb[t];
    s += o;
    e0 = fmaf(o, rv.x, e0);
    e1 = fmaf(o, rv.y, e1);
  }
  float inv = 1.0f / (s + 5.12e-8f);  // + T*1e-10
  ((float2*)EC)[b * NOUT + n] = make_float2(e0 * inv, e1 * inv);
}

// ---------------------------------------------------------------------------
// Kernel D2: EP[b,t,:] = (sum_n out*EC) / (sum_n out + N*1e-10)
// ---------------------------------------------------------------------------
__global__ __launch_bounds__(256) void ep_kernel(
    const float* __restrict__ out, const float* __restrict__ EC,
    float* __restrict__ EP) {
  const int b = blockIdx.x;
  const int tid = threadIdx.x;
  const int lane = tid & 63, wave = tid >> 6;
  __shared__ float ec0[NOUT], ec1[NOUT];

  float2 e = ((const float2*)EC)[b * NOUT + tid];
  ec0[tid] = e.x;
  ec1[tid] = e.y;
  __syncthreads();

  float4 c0 = *(const float4*)&ec0[lane * 4];
  float4 c1 = *(const float4*)&ec1[lane * 4];

  const float* ob = out + (size_t)b * TT * NOUT;
  float2* epb = (float2*)EP + (size_t)b * TT;

  for (int t = wave; t < TT; t += 4) {
    float4 o = *(const float4*)&ob[t * NOUT + lane * 4];
    float s = o.x + o.y + o.z + o.w;
    float a0 = o.x * c0.x + o.y * c0.y + o.z * c0.z + o.w * c0.w;
    float a1 = o.x * c1.x + o.y * c1.y + o.z * c1.z + o.w * c1.w;
#pragma unroll
    for (int off = 32; off > 0; off >>= 1) {
      s += __shfl_down(s, off);
      a0 += __shfl_down(a0, off);
      a1 += __shfl_down(a1, off);
    }
    if (lane == 0) {
      float inv = 1.0f / (s + 2.56e-8f);  // + NOUT*1e-10
      epb[t] = make_float2(a0 * inv, a1 * inv);
    }
  }
}

// ---------------------------------------------------------------------------
extern "C" void kernel_launch(void* const* d_in, const int* in_sizes, int n_in,
                              void* d_out, int out_size, void* d_ws,
                              size_t ws_size, hipStream_t stream) {
  const float* vel = (const float*)d_in[0];
  const float* r = (const float*)d_in[1];
  const float* start_state = (const float*)d_in[2];
  const float* W_speed = (const float*)d_in[3];
  const float* W_hd = (const float*)d_in[4];
  const float* W_rec = (const float*)d_in[5];
  const float* b_rec = (const float*)d_in[6];
  const float* W_out = (const float*)d_in[7];
  const float* b_out = (const float*)d_in[8];
  float* EP = (float*)d_out;

  char* ws = (char*)d_ws;
  float* drive = (float*)ws;                          // 64 MB
  float* hstates = (float*)(ws + (size_t)67108864);   // 64 MB
  float* outbuf = (float*)ws;                         // reuses drive region
  float* EC = (float*)(ws + (size_t)134217728);       // 128 KB

  feat_drive_kernel<<<512, 256, 0, stream>>>(vel, W_speed, W_hd, b_rec, drive);
  rnn_scan_kernel<<<64, 256, 0, stream>>>(drive, W_rec, start_state, hstates);
  out_gemm_kernel<<<dim3(512, 4), 256, 0, stream>>>(hstates, W_out, b_out,
                                                    outbuf);
  ec_kernel<<<64, 256, 0, stream>>>(outbuf, r, EC);
  ep_kernel<<<64, 256, 0, stream>>>(outbuf, EC, EP);
}

// Round 6
// 4249.947 us; speedup vs baseline: 1.8439x; 1.8439x over previous
//
#include <hip/hip_runtime.h>
#include <hip/hip_bf16.h>

// Problem constants
#define BATCH 64
#define TT 512
#define UNITS 512
#define NOUT 256
#define NSPEED 20
#define NHD 50
#define NFEAT 70

// Derived constants
#define SPEED_COEF (-800.0f)                  // -0.5/sd^2, sd = 0.5/20
#define SPEED_STEP (0.5f / 19.0f)             // linspace(0,0.5,20)
#define HD_STEP (6.28318530718f / 49.0f)      // linspace(0,2pi,50)
#define KAPPA 6.2831853f
#define C_HD 0.9783857f                       // 1 / (2*pi*i0e(2*pi)), i0e(2pi)=0.162671

// ---------------------------------------------------------------------------
// Kernel P: repack W_rec f32 [k][col] -> float4 tiles wp[k4][col] where
// wp[k4*512+col] = (W[4k4+0][col], W[4k4+1][col], W[4k4+2][col], W[4k4+3][col])
// Consecutive lanes (col) read consecutive float4 -> 1 KB coalesced wave loads.
// ---------------------------------------------------------------------------
__global__ __launch_bounds__(256) void prep_w4_kernel(
    const float* __restrict__ W, float4* __restrict__ wp) {
  int idx = blockIdx.x * 256 + threadIdx.x;  // 65536 = 128 k4-groups * 512 cols
  int k4 = idx >> 9, col = idx & 511;
  const float* w0 = W + (size_t)(k4 * 4) * UNITS + col;
  wp[idx] = make_float4(w0[0], w0[UNITS], w0[2 * UNITS], w0[3 * UNITS]);
}

// ---------------------------------------------------------------------------
// Kernel A: RBF/VonMises features + drive = sf@W_speed + hf@W_hd + b_rec
// ---------------------------------------------------------------------------
__global__ __launch_bounds__(256) void feat_drive_kernel(
    const float* __restrict__ vel, const float* __restrict__ W_speed,
    const float* __restrict__ W_hd, const float* __restrict__ b_rec,
    float* __restrict__ drive) {
  __shared__ float feats[64][NFEAT];
  const int row0 = blockIdx.x * 64;
  const int tid = threadIdx.x;

  for (int j = tid; j < 64 * NFEAT; j += 256) {
    int row = j / NFEAT, k = j % NFEAT;
    int grow = row0 + row;
    float f;
    if (k < NSPEED) {
      float s = vel[grow * 2 + 0];
      float d = s - (float)k * SPEED_STEP;
      f = __expf(SPEED_COEF * d * d);
    } else {
      float hd = vel[grow * 2 + 1];
      float c = (float)(k - NSPEED) * HD_STEP;
      f = C_HD * __expf(KAPPA * (__cosf(hd - c) - 1.0f));
    }
    feats[row][k] = f;
  }
  __syncthreads();

  const float2* Ws2 = (const float2*)W_speed;  // [20][256]
  const float2* Wh2 = (const float2*)W_hd;     // [50][256]
  float2 br = ((const float2*)b_rec)[tid];

  for (int r = 0; r < 64; ++r) {
    float a0 = br.x, a1 = br.y;
#pragma unroll
    for (int k = 0; k < NSPEED; ++k) {
      float f = feats[r][k];
      float2 w = Ws2[k * 256 + tid];
      a0 = fmaf(f, w.x, a0);
      a1 = fmaf(f, w.y, a1);
    }
#pragma unroll 10
    for (int k = 0; k < NHD; ++k) {
      float f = feats[r][NSPEED + k];
      float2 w = Wh2[k * 256 + tid];
      a0 = fmaf(f, w.x, a0);
      a1 = fmaf(f, w.y, a1);
    }
    ((float2*)drive)[(size_t)(row0 + r) * 256 + tid] = make_float2(a0, a1);
  }
}

// ---------------------------------------------------------------------------
// Kernel B: sequential RNN scan, f32 weights. 64 blocks x 1024 threads
// (16 waves/CU). Thread = (col, k-half); 2-way K-split combined via LDS.
// W streamed from L2 as coalesced float4 (1 KB per wave-load); 8-deep
// unroll keeps ~128 KB/CU in flight -> L2 latency hidden, link-BW-bound.
// ---------------------------------------------------------------------------
__global__ __launch_bounds__(1024) void rnn_scan3_kernel(
    const float4* __restrict__ wp, const float* __restrict__ drive,
    const float* __restrict__ start_state, float* __restrict__ hstates) {
  __shared__ __align__(16) float hf[UNITS];
  __shared__ float pt[UNITS];
  const int b = blockIdx.x;
  const int tid = threadIdx.x;
  const int col = tid & 511;
  const int ks = tid >> 9;  // k-half: wave-uniform

  if (tid < UNITS) hf[tid] = start_state[tid];
  __syncthreads();

  const float4* wb = wp + (ks << 15) + col;        // (ks*64 + g)*512 + col
  const float4* hp = (const float4*)hf + (ks << 6);  // 64 float4 per half
  const float* D = drive + (size_t)b * TT * UNITS;
  float* H = hstates + (size_t)b * TT * UNITS;

  for (int t = 0; t < TT; ++t) {
    float a0 = 0.f, a1 = 0.f, a2 = 0.f, a3 = 0.f;
#pragma unroll 8
    for (int g = 0; g < 64; ++g) {
      float4 w = wb[g << 9];
      float4 h4 = hp[g];  // wave-uniform LDS broadcast
      a0 = fmaf(h4.x, w.x, a0);
      a1 = fmaf(h4.y, w.y, a1);
      a2 = fmaf(h4.z, w.z, a2);
      a3 = fmaf(h4.w, w.w, a3);
    }
    float acc = (a0 + a1) + (a2 + a3);
    if (ks) pt[col] = acc;
    __syncthreads();
    if (!ks) {
      float hn = fmaxf(acc + pt[col] + D[t * UNITS + col], 0.0f);
      hf[col] = hn;
      H[t * UNITS + col] = hn;
    }
    __syncthreads();
  }
}

// ---------------------------------------------------------------------------
// Kernel C: out = relu(hstates @ W_out + b_out); M=32768, N=256, K=512
// ---------------------------------------------------------------------------
__global__ __launch_bounds__(256) void out_gemm_kernel(
    const float* __restrict__ A,    // [32768][512]
    const float* __restrict__ Bm,   // [512][256]
    const float* __restrict__ b_out,
    float* __restrict__ C) {        // [32768][256]
  __shared__ float As[32][68];  // transposed, padded
  __shared__ float Bs[32][64];
  const int bm = blockIdx.x, bn = blockIdx.y;
  const int tid = threadIdx.x;
  const int tm = tid / 16, tn = tid % 16;

  float acc[4][4] = {{0.f}};

  for (int k0 = 0; k0 < UNITS; k0 += 32) {
    {
      int ar = tid / 8;
      int ac = (tid % 8) * 4;
#pragma unroll
      for (int p = 0; p < 2; ++p) {
        int row = ar + p * 32;
        float4 v = *(const float4*)&A[(size_t)(bm * 64 + row) * 512 + k0 + ac];
        As[ac + 0][row] = v.x;
        As[ac + 1][row] = v.y;
        As[ac + 2][row] = v.z;
        As[ac + 3][row] = v.w;
      }
      int brr = tid / 16;
      int bc = (tid % 16) * 4;
#pragma unroll
      for (int p = 0; p < 2; ++p) {
        int row = brr + p * 16;
        *(float4*)&Bs[row][bc] =
            *(const float4*)&Bm[(size_t)(k0 + row) * 256 + bn * 64 + bc];
      }
    }
    __syncthreads();
#pragma unroll
    for (int kk = 0; kk < 32; ++kk) {
      float4 av = *(const float4*)&As[kk][tm * 4];
      float4 bv = *(const float4*)&Bs[kk][tn * 4];
      acc[0][0] = fmaf(av.x, bv.x, acc[0][0]);
      acc[0][1] = fmaf(av.x, bv.y, acc[0][1]);
      acc[0][2] = fmaf(av.x, bv.z, acc[0][2]);
      acc[0][3] = fmaf(av.x, bv.w, acc[0][3]);
      acc[1][0] = fmaf(av.y, bv.x, acc[1][0]);
      acc[1][1] = fmaf(av.y, bv.y, acc[1][1]);
      acc[1][2] = fmaf(av.y, bv.z, acc[1][2]);
      acc[1][3] = fmaf(av.y, bv.w, acc[1][3]);
      acc[2][0] = fmaf(av.z, bv.x, acc[2][0]);
      acc[2][1] = fmaf(av.z, bv.y, acc[2][1]);
      acc[2][2] = fmaf(av.z, bv.z, acc[2][2]);
      acc[2][3] = fmaf(av.z, bv.w, acc[2][3]);
      acc[3][0] = fmaf(av.w, bv.x, acc[3][0]);
      acc[3][1] = fmaf(av.w, bv.y, acc[3][1]);
      acc[3][2] = fmaf(av.w, bv.z, acc[3][2]);
      acc[3][3] = fmaf(av.w, bv.w, acc[3][3]);
    }
    __syncthreads();
  }

  float4 bo = *(const float4*)&b_out[bn * 64 + tn * 4];
#pragma unroll
  for (int i = 0; i < 4; ++i) {
    int row = bm * 64 + tm * 4 + i;
    float4 o;
    o.x = fmaxf(acc[i][0] + bo.x, 0.0f);
    o.y = fmaxf(acc[i][1] + bo.y, 0.0f);
    o.z = fmaxf(acc[i][2] + bo.z, 0.0f);
    o.w = fmaxf(acc[i][3] + bo.w, 0.0f);
    *(float4*)&C[(size_t)row * 256 + bn * 64 + tn * 4] = o;
  }
}

// ---------------------------------------------------------------------------
// Kernel D1: EC[b,n,:] = (sum_t out*r) / (sum_t out + T*1e-10)
// ---------------------------------------------------------------------------
__global__ __launch_bounds__(256) void ec_kernel(
    const float* __restrict__ out, const float* __restrict__ r,
    float* __restrict__ EC) {  // [64][256][2]
  const int b = blockIdx.x, n = threadIdx.x;
  const float* ob = out + (size_t)b * TT * NOUT;
  const float2* rb = (const float2*)r + (size_t)b * TT;
  float s = 0.0f, e0 = 0.0f, e1 = 0.0f;
  for (int t = 0; t < TT; ++t) {
    float o = ob[t * NOUT + n];
    float2 rv = rb[t];
    s += o;
    e0 = fmaf(o, rv.x, e0);
    e1 = fmaf(o, rv.y, e1);
  }
  float inv = 1.0f / (s + 5.12e-8f);  // + T*1e-10
  ((float2*)EC)[b * NOUT + n] = make_float2(e0 * inv, e1 * inv);
}

// ---------------------------------------------------------------------------
// Kernel D2: EP[b,t,:] = (sum_n out*EC) / (sum_n out + N*1e-10)
// ---------------------------------------------------------------------------
__global__ __launch_bounds__(256) void ep_kernel(
    const float* __restrict__ out, const float* __restrict__ EC,
    float* __restrict__ EP) {
  const int b = blockIdx.x;
  const int tid = threadIdx.x;
  const int lane = tid & 63, wave = tid >> 6;
  __shared__ float ec0[NOUT], ec1[NOUT];

  float2 e = ((const float2*)EC)[b * NOUT + tid];
  ec0[tid] = e.x;
  ec1[tid] = e.y;
  __syncthreads();

  float4 c0 = *(const float4*)&ec0[lane * 4];
  float4 c1 = *(const float4*)&ec1[lane * 4];

  const float* ob = out + (size_t)b * TT * NOUT;
  float2* epb = (float2*)EP + (size_t)b * TT;

  for (int t = wave; t < TT; t += 4) {
    float4 o = *(const float4*)&ob[t * NOUT + lane * 4];
    float s = o.x + o.y + o.z + o.w;
    float a0 = o.x * c0.x + o.y * c0.y + o.z * c0.z + o.w * c0.w;
    float a1 = o.x * c1.x + o.y * c1.y + o.z * c1.z + o.w * c1.w;
#pragma unroll
    for (int off = 32; off > 0; off >>= 1) {
      s += __shfl_down(s, off);
      a0 += __shfl_down(a0, off);
      a1 += __shfl_down(a1, off);
    }
    if (lane == 0) {
      float inv = 1.0f / (s + 2.56e-8f);  // + NOUT*1e-10
      epb[t] = make_float2(a0 * inv, a1 * inv);
    }
  }
}

// ---------------------------------------------------------------------------
extern "C" void kernel_launch(void* const* d_in, const int* in_sizes, int n_in,
                              void* d_out, int out_size, void* d_ws,
                              size_t ws_size, hipStream_t stream) {
  const float* vel = (const float*)d_in[0];
  const float* r = (const float*)d_in[1];
  const float* start_state = (const float*)d_in[2];
  const float* W_speed = (const float*)d_in[3];
  const float* W_hd = (const float*)d_in[4];
  const float* W_rec = (const float*)d_in[5];
  const float* b_rec = (const float*)d_in[6];
  const float* W_out = (const float*)d_in[7];
  const float* b_out = (const float*)d_in[8];
  float* EP = (float*)d_out;

  char* ws = (char*)d_ws;
  float* drive = (float*)ws;                            // 64 MB
  float* hstates = (float*)(ws + (size_t)67108864);     // 64 MB
  float* outbuf = (float*)ws;                           // reuses drive region
  float4* wpack = (float4*)(ws + (size_t)134217728);    // 1 MB repacked W_rec
  float* EC = (float*)(ws + (size_t)135266304);         // 128 KB

  prep_w4_kernel<<<256, 256, 0, stream>>>(W_rec, wpack);
  feat_drive_kernel<<<512, 256, 0, stream>>>(vel, W_speed, W_hd, b_rec, drive);
  rnn_scan3_kernel<<<64, 1024, 0, stream>>>(wpack, drive, start_state,
                                            hstates);
  out_gemm_kernel<<<dim3(512, 4), 256, 0, stream>>>(hstates, W_out, b_out,
                                                    outbuf);
  ec_kernel<<<64, 256, 0, stream>>>(outbuf, r, EC);
  ep_kernel<<<64, 256, 0, stream>>>(outbuf, EC, EP);
}